// Round 1
// baseline (94.397 us; speedup 1.0000x reference)
//
#include <hip/hip_runtime.h>

#define BB 4
#define MM 128
#define LL 512
#define DD 768
#define NEGF (-1e30f)

// Block: 512 threads = 8 waves. Wave w owns l-chunk [w*64, w*64+64).
// Lane -> d within a 64-wide d-chunk. Grid: (D/64=12, M/16=8, B=4).
// h tile staged in 64 VGPRs per thread; mask handled as wave-uniform
// ballot bits -> scalar-branch-guarded v_max (masked tokens cost 0 VALU).
__global__ __launch_bounds__(512, 4) void mention_max_kernel(
    const float* __restrict__ h, const int* __restrict__ mask,
    float* __restrict__ out)
{
    const int lane = threadIdx.x & 63;
    const int wave = threadIdx.x >> 6;   // 0..7 : l-chunk id
    const int dch  = blockIdx.x;         // 0..11
    const int mch  = blockIdx.y;         // 0..7
    const int b    = blockIdx.z;         // 0..3
    const int d    = dch * 64 + lane;
    const int l0   = wave * 64;

    // Stage h[b][l0+i][d] for i in 0..63 into registers (coalesced per row).
    float hreg[64];
    const float* hp = h + ((size_t)b * LL + l0) * DD + d;
#pragma unroll
    for (int i = 0; i < 64; ++i) hreg[i] = hp[(size_t)i * DD];

    __shared__ float red[8][16][64];     // 32 KB: [wave][m][lane]

    const int m0 = mch * 16;
    const int* mp = mask + ((size_t)b * MM + m0) * LL + l0 + lane;

#pragma unroll 1
    for (int m = 0; m < 16; ++m) {
        // lane <-> l within chunk: coalesced 64-int load, ballot -> uniform bits
        unsigned long long bits = __ballot(mp[(size_t)m * LL] != 0);
        float a0 = NEGF, a1 = NEGF;      // 2 accumulators: break dep chain
#pragma unroll
        for (int i = 0; i < 64; i += 2) {
            if (bits & (1ull << i))       a0 = fmaxf(a0, hreg[i]);
            if (bits & (1ull << (i + 1))) a1 = fmaxf(a1, hreg[i + 1]);
        }
        red[wave][m][lane] = fmaxf(a0, a1);
    }
    __syncthreads();

    // 8-wave tree reduce: 1024 outputs, 512 threads -> 2 each.
#pragma unroll
    for (int r = 0; r < 2; ++r) {
        int o  = (int)threadIdx.x + r * 512;  // 0..1023
        int m  = o >> 6;
        int ln = o & 63;
        float v = red[0][m][ln];
#pragma unroll
        for (int w = 1; w < 8; ++w) v = fmaxf(v, red[w][m][ln]);
        out[((size_t)b * MM + m0 + m) * DD + dch * 64 + ln] = v;
    }
}

extern "C" void kernel_launch(void* const* d_in, const int* in_sizes, int n_in,
                              void* d_out, int out_size, void* d_ws, size_t ws_size,
                              hipStream_t stream) {
    const float* h    = (const float*)d_in[0];
    const int*   mask = (const int*)d_in[1];
    float*       out  = (float*)d_out;
    dim3 grid(DD / 64, MM / 16, BB);
    mention_max_kernel<<<grid, dim3(512), 0, stream>>>(h, mask, out);
}

// Round 2
// 84.799 us; speedup vs baseline: 1.1132x; 1.1132x over previous
//
#include <hip/hip_runtime.h>

#define BB 4
#define MM 128
#define LL 512
#define DD 768
#define NEGF (-1e30f)

// 256 threads = 4 waves. Wave w covers l in [w*128, w*128+128) via two
// register-staged chunks of 64 rows. Lane holds float2 of d (d-chunk = 128).
// Grid: (D/128=6, M/8=16, B=4) = 384 blocks, ~3 blocks/CU capacity.
// Mask handled as wave-uniform ballot bits -> branchless scalar-selected
// addend (0 or -1e30) + v_add(sgpr) + v_max3. Exactly reference arithmetic.
__global__ __launch_bounds__(256, 3) void mention_max_kernel(
    const float* __restrict__ h, const int* __restrict__ mask,
    float* __restrict__ out)
{
    const int lane = threadIdx.x & 63;
    const int wave = threadIdx.x >> 6;   // 0..3
    const int dch  = blockIdx.x;         // 0..5
    const int mch  = blockIdx.y;         // 0..15
    const int b    = blockIdx.z;         // 0..3

    const int d0 = dch * 128 + lane * 2;
    const int m0 = mch * 8;

    float2 acc[8];
#pragma unroll
    for (int m = 0; m < 8; ++m) acc[m] = make_float2(NEGF, NEGF);

#pragma unroll 1
    for (int s = 0; s < 2; ++s) {
        const int l0 = wave * 128 + s * 64;
        // Stage h[b][l0+i][d0..d0+1] in 128 VGPRs (coalesced 512B/row-instr).
        const float2* hp = (const float2*)(h + ((size_t)(b * LL + l0)) * DD + d0);
        float2 hreg[64];
#pragma unroll
        for (int i = 0; i < 64; ++i) hreg[i] = hp[(size_t)i * (DD / 2)];

        const int* mp = mask + ((size_t)(b * MM + m0)) * LL + l0 + lane;
#pragma unroll 1
        for (int m = 0; m < 8; ++m) {
            unsigned long long bits = __ballot(mp[m * LL] != 0);
            unsigned lo = (unsigned)bits;
            unsigned hi = (unsigned)(bits >> 32);
            float ax = acc[m].x, ay = acc[m].y;
#pragma unroll
            for (int i = 0; i < 32; i += 2) {
                float ad0 = ((lo >> i) & 1u) ? 0.0f : NEGF;
                float ad1 = ((lo >> (i + 1)) & 1u) ? 0.0f : NEGF;
                ax = fmaxf(ax, fmaxf(hreg[i].x + ad0, hreg[i + 1].x + ad1));
                ay = fmaxf(ay, fmaxf(hreg[i].y + ad0, hreg[i + 1].y + ad1));
            }
#pragma unroll
            for (int i = 0; i < 32; i += 2) {
                float ad0 = ((hi >> i) & 1u) ? 0.0f : NEGF;
                float ad1 = ((hi >> (i + 1)) & 1u) ? 0.0f : NEGF;
                ax = fmaxf(ax, fmaxf(hreg[32 + i].x + ad0, hreg[33 + i].x + ad1));
                ay = fmaxf(ay, fmaxf(hreg[32 + i].y + ad0, hreg[33 + i].y + ad1));
            }
            acc[m].x = ax;
            acc[m].y = ay;
        }
    }

    __shared__ float2 red[4][8][64];     // 16 KB
#pragma unroll
    for (int m = 0; m < 8; ++m) red[wave][m][lane] = acc[m];
    __syncthreads();

    // 1024 output floats = 512 float2; 256 threads x 2.
#pragma unroll
    for (int r = 0; r < 2; ++r) {
        int o  = (int)threadIdx.x + r * 256;  // 0..511
        int m  = o >> 6;
        int dp = o & 63;
        float2 v = red[0][m][dp];
#pragma unroll
        for (int w = 1; w < 4; ++w) {
            float2 u = red[w][m][dp];
            v.x = fmaxf(v.x, u.x);
            v.y = fmaxf(v.y, u.y);
        }
        ((float2*)(out + ((size_t)(b * MM + m0 + m)) * DD + dch * 128))[dp] = v;
    }
}

extern "C" void kernel_launch(void* const* d_in, const int* in_sizes, int n_in,
                              void* d_out, int out_size, void* d_ws, size_t ws_size,
                              hipStream_t stream) {
    const float* h    = (const float*)d_in[0];
    const int*   mask = (const int*)d_in[1];
    float*       out  = (float*)d_out;
    dim3 grid(DD / 128, MM / 8, BB);
    mention_max_kernel<<<grid, dim3(256), 0, stream>>>(h, mask, out);
}

// Round 3
// 74.581 us; speedup vs baseline: 1.2657x; 1.1370x over previous
//
#include <hip/hip_runtime.h>

#define BB 4
#define MM 128
#define LL 512
#define DD 768
#define NEGF (-1e30f)

// 512 threads = 8 waves; wave w owns l in [w*64, w*64+64), staged as two
// 32-row halves of float2 (64 VGPRs -- no spill under the 128-reg cap).
// Lane holds 2 d values (d-chunk 128). Grid (6,16,4)=384 blocks, 3 waves/SIMD.
// Mask -> one 64-bit ballot per (wave,m), kept in SGPRs; branchless scalar
// cselect addend (0 / -1e30) + v_add + v_max3. Exactly reference arithmetic.
__global__ __launch_bounds__(512, 4) void mention_max_kernel(
    const float* __restrict__ h, const int* __restrict__ mask,
    float* __restrict__ out)
{
    const int lane = threadIdx.x & 63;
    const int wave = threadIdx.x >> 6;   // 0..7
    const int dch  = blockIdx.x;         // 0..5
    const int mch  = blockIdx.y;         // 0..15
    const int b    = blockIdx.z;         // 0..3

    const int d0 = dch * 128 + lane * 2;
    const int m0 = mch * 8;
    const int l0 = wave * 64;

    // Prefetch 8 mask words + ballots up front (latencies overlap).
    const int* mp = mask + ((size_t)(b * MM + m0)) * LL + l0 + lane;
    unsigned blo[8], bhi[8];
#pragma unroll
    for (int m = 0; m < 8; ++m) {
        unsigned long long bits = __ballot(mp[m * LL] != 0);
        blo[m] = (unsigned)__builtin_amdgcn_readfirstlane((int)(unsigned)bits);
        bhi[m] = (unsigned)__builtin_amdgcn_readfirstlane((int)(unsigned)(bits >> 32));
    }

    float2 acc[8];
#pragma unroll
    for (int m = 0; m < 8; ++m) acc[m] = make_float2(NEGF, NEGF);

#pragma unroll
    for (int s = 0; s < 2; ++s) {
        // Stage rows [l0+s*32, l0+s*32+32): 64 VGPRs, coalesced 512B/row.
        const float2* hp =
            (const float2*)(h + ((size_t)(b * LL + l0 + s * 32)) * DD + d0);
        float2 hreg[32];
#pragma unroll
        for (int i = 0; i < 32; ++i) hreg[i] = hp[(size_t)i * (DD / 2)];

#pragma unroll
        for (int m = 0; m < 8; ++m) {
            const unsigned w32 = s ? bhi[m] : blo[m];
            float ax = acc[m].x, ay = acc[m].y;
#pragma unroll
            for (int i = 0; i < 32; i += 2) {
                const float ad0 = ((w32 >> i) & 1u) ? 0.0f : NEGF;
                const float ad1 = ((w32 >> (i + 1)) & 1u) ? 0.0f : NEGF;
                ax = fmaxf(ax, fmaxf(hreg[i].x + ad0, hreg[i + 1].x + ad1));
                ay = fmaxf(ay, fmaxf(hreg[i].y + ad0, hreg[i + 1].y + ad1));
            }
            acc[m].x = ax;
            acc[m].y = ay;
        }
    }

    __shared__ float2 red[8][8][64];     // 32 KB
#pragma unroll
    for (int m = 0; m < 8; ++m) red[wave][m][lane] = acc[m];
    __syncthreads();

    // 1024 output floats = 512 float2; one per thread.
    {
        const int o  = (int)threadIdx.x;  // 0..511
        const int m  = o >> 6;
        const int dp = o & 63;
        float2 v = red[0][m][dp];
#pragma unroll
        for (int w = 1; w < 8; ++w) {
            const float2 u = red[w][m][dp];
            v.x = fmaxf(v.x, u.x);
            v.y = fmaxf(v.y, u.y);
        }
        ((float2*)(out + ((size_t)(b * MM + m0 + m)) * DD + dch * 128))[dp] = v;
    }
}

extern "C" void kernel_launch(void* const* d_in, const int* in_sizes, int n_in,
                              void* d_out, int out_size, void* d_ws, size_t ws_size,
                              hipStream_t stream) {
    const float* h    = (const float*)d_in[0];
    const int*   mask = (const int*)d_in[1];
    float*       out  = (float*)d_out;
    dim3 grid(DD / 128, MM / 8, BB);
    mention_max_kernel<<<grid, dim3(512), 0, stream>>>(h, mask, out);
}

// Round 4
// 74.181 us; speedup vs baseline: 1.2725x; 1.0054x over previous
//
#include <hip/hip_runtime.h>

#define BB 4
#define MM 128
#define LL 512
#define DD 768
#define NEGF (-1e30f)

// Kernel1: 256 threads = 4 waves. Grid (6 dch, 32 = mch*2+lhalf, 4 b) = 768
// blocks -> exactly 3 blocks/CU, 12 waves/CU uniform (no 2-vs-1 block tail).
// Wave owns 64 l rows (two 32-row register stages, 64 VGPRs), lane holds
// float2 of d (d-chunk 128). Mask: one 64-bit ballot per (wave,m); addend
// built by BRANCHLESS uniform bit-arith (no ?: -- LLVM branchifies uniform
// selects): rep = (int)(w32<<(31-k))>>31; ad = ~rep & bits(-1e30f).
// Exactly reference arithmetic (add bit-exact -1e30 then max). Partials for
// the two l-halves go to d_ws; kernel2 maxes them into d_out.
__global__ __launch_bounds__(256, 3) void mention_max_part(
    const float* __restrict__ h, const int* __restrict__ mask,
    float* __restrict__ ws)
{
    const int lane = threadIdx.x & 63;
    const int wave = threadIdx.x >> 6;     // 0..3
    const int dch  = blockIdx.x;           // 0..5
    const int mch  = blockIdx.y >> 1;      // 0..15
    const int lh   = blockIdx.y & 1;       // 0..1
    const int b    = blockIdx.z;           // 0..3

    const int d0 = dch * 128 + lane * 2;
    const int m0 = mch * 8;
    const int l0 = lh * 256 + wave * 64;

    const unsigned NEGB = __float_as_uint(NEGF);

    // Ballots up front (8 coalesced mask loads overlap).
    const int* mp = mask + ((size_t)(b * MM + m0)) * LL + l0 + lane;
    unsigned blo[8], bhi[8];
#pragma unroll
    for (int m = 0; m < 8; ++m) {
        unsigned long long bits = __ballot(mp[m * LL] != 0);
        blo[m] = (unsigned)bits;
        bhi[m] = (unsigned)(bits >> 32);
    }

    float2 acc[8];
#pragma unroll
    for (int m = 0; m < 8; ++m) acc[m] = make_float2(NEGF, NEGF);

#pragma unroll
    for (int s = 0; s < 2; ++s) {
        const float2* hp =
            (const float2*)(h + ((size_t)(b * LL + l0 + s * 32)) * DD + d0);
        float2 hreg[32];
#pragma unroll
        for (int i = 0; i < 32; ++i) hreg[i] = hp[(size_t)i * (DD / 2)];

#pragma unroll
        for (int m = 0; m < 8; ++m) {
            const unsigned w32 = s ? bhi[m] : blo[m];
            float ax = acc[m].x, ay = acc[m].y;
#pragma unroll
            for (int i = 0; i < 32; i += 2) {
                // branchless uniform addend: 0.0f if bit set, else -1e30f
                const unsigned r0 = (unsigned)((int)(w32 << (31 - i)) >> 31);
                const unsigned r1 = (unsigned)((int)(w32 << (30 - i)) >> 31);
                const float ad0 = __uint_as_float(~r0 & NEGB);
                const float ad1 = __uint_as_float(~r1 & NEGB);
                ax = fmaxf(ax, fmaxf(hreg[i].x + ad0, hreg[i + 1].x + ad1));
                ay = fmaxf(ay, fmaxf(hreg[i].y + ad0, hreg[i + 1].y + ad1));
            }
            acc[m].x = ax;
            acc[m].y = ay;
        }
    }

    __shared__ float2 red[4][8][64];       // 16 KB
#pragma unroll
    for (int m = 0; m < 8; ++m) red[wave][m][lane] = acc[m];
    __syncthreads();

    // 1024 partial floats = 512 float2; 256 threads x 2.
#pragma unroll
    for (int r = 0; r < 2; ++r) {
        const int o  = (int)threadIdx.x + r * 256;  // 0..511
        const int m  = o >> 6;
        const int dp = o & 63;
        float2 v = red[0][m][dp];
#pragma unroll
        for (int w = 1; w < 4; ++w) {
            const float2 u = red[w][m][dp];
            v.x = fmaxf(v.x, u.x);
            v.y = fmaxf(v.y, u.y);
        }
        // ws layout: [lh][b][m][d]
        ((float2*)(ws + ((size_t)lh * BB * MM * DD) +
                   ((size_t)(b * MM + m0 + m)) * DD + dch * 128))[dp] = v;
    }
}

// Kernel2: out = max(ws_half0, ws_half1), elementwise over B*M*D floats.
__global__ __launch_bounds__(256) void mention_max_merge(
    const float* __restrict__ ws, float* __restrict__ out)
{
    const int i = (int)(blockIdx.x * blockDim.x + threadIdx.x);  // float4 idx
    const float4* p0 = (const float4*)ws;
    const float4* p1 = (const float4*)(ws + (size_t)BB * MM * DD);
    const float4 a = p0[i], b = p1[i];
    float4 v;
    v.x = fmaxf(a.x, b.x);
    v.y = fmaxf(a.y, b.y);
    v.z = fmaxf(a.z, b.z);
    v.w = fmaxf(a.w, b.w);
    ((float4*)out)[i] = v;
}

extern "C" void kernel_launch(void* const* d_in, const int* in_sizes, int n_in,
                              void* d_out, int out_size, void* d_ws, size_t ws_size,
                              hipStream_t stream) {
    const float* h    = (const float*)d_in[0];
    const int*   mask = (const int*)d_in[1];
    float*       out  = (float*)d_out;
    float*       ws   = (float*)d_ws;
    dim3 grid1(DD / 128, (MM / 8) * 2, BB);
    mention_max_part<<<grid1, dim3(256), 0, stream>>>(h, mask, ws);
    const int n4 = BB * MM * DD / 4;       // 98304 float4
    mention_max_merge<<<n4 / 256, dim3(256), 0, stream>>>(ws, out);
}

// Round 5
// 72.320 us; speedup vs baseline: 1.3053x; 1.0257x over previous
//
#include <hip/hip_runtime.h>

#define BB 4
#define MM 128
#define LL 512
#define DD 768
#define NEGF (-1e30f)

// Kernel1: 256 thr = 4 waves. Grid (3 dch, 16 mch * 4 lh, 4 b) = 768 blocks
// -> 3 blocks/CU uniform, 12 waves/CU. Lane holds float4 of d (d-chunk 256),
// so one per-l select feeds 4 outputs (SALU/elem ~0.5). Wave owns 32 l as two
// 16-row float4 register stages (64 VGPR). Inner: t=h+ad pairs folded
// max3-style -> ~1.5 VALU/elem. Exactly reference arithmetic (add bit-exact
// -1e30 then max; empty-active rows give exactly -1e30). Partials per lh go
// to d_ws; kernel2 maxes the 4 halves into d_out.
__global__ __launch_bounds__(256, 3) void mention_max_part(
    const float* __restrict__ h, const int* __restrict__ mask,
    float* __restrict__ ws)
{
    const int lane = threadIdx.x & 63;
    const int wave = threadIdx.x >> 6;     // 0..3
    const int dch  = blockIdx.x;           // 0..2
    const int mch  = blockIdx.y >> 2;      // 0..15
    const int lh   = blockIdx.y & 3;       // 0..3
    const int b    = blockIdx.z;           // 0..3

    const int d0 = dch * 256 + lane * 4;
    const int m0 = mch * 8;
    const int l0 = lh * 128 + wave * 32;   // wave owns [l0, l0+32)

    // Mask pointer, lane->l, clamped so lanes >=32 stay in bounds (their
    // ballot bits are ignored; we consume only bits 0..31).
    const int lclamp = (l0 + lane < LL) ? (l0 + lane) : (LL - 1);
    const int* mp = mask + ((size_t)(b * MM + m0)) * LL + lclamp;

    unsigned bits[8];
#pragma unroll
    for (int m = 0; m < 8; ++m) {
        unsigned long long bl = __ballot(mp[m * LL] != 0);
        bits[m] = (unsigned)__builtin_amdgcn_readfirstlane((int)(unsigned)bl);
    }

    float4 acc[8];
#pragma unroll
    for (int m = 0; m < 8; ++m) acc[m] = make_float4(NEGF, NEGF, NEGF, NEGF);

#pragma unroll
    for (int s = 0; s < 2; ++s) {
        // Stage rows [l0+s*16, l0+s*16+16): 16 x float4 = 64 VGPRs.
        const float4* hp =
            (const float4*)(h + ((size_t)(b * LL + l0 + s * 16)) * DD + d0);
        float4 hreg[16];
#pragma unroll
        for (int i = 0; i < 16; ++i) hreg[i] = hp[(size_t)i * (DD / 4)];

#pragma unroll
        for (int m = 0; m < 8; ++m) {
            const unsigned w = bits[m];
            float4 a = acc[m];
#pragma unroll
            for (int i = 0; i < 16; i += 2) {
                const int k = s * 16 + i;  // bit index within the 32 used
                const float ad0 = ((w >> k) & 1u) ? 0.0f : NEGF;
                const float ad1 = ((w >> (k + 1)) & 1u) ? 0.0f : NEGF;
                a.x = fmaxf(fmaxf(hreg[i].x + ad0, hreg[i + 1].x + ad1), a.x);
                a.y = fmaxf(fmaxf(hreg[i].y + ad0, hreg[i + 1].y + ad1), a.y);
                a.z = fmaxf(fmaxf(hreg[i].z + ad0, hreg[i + 1].z + ad1), a.z);
                a.w = fmaxf(fmaxf(hreg[i].w + ad0, hreg[i + 1].w + ad1), a.w);
            }
            acc[m] = a;
        }
    }

    __shared__ float4 red[4][8][64];       // 32 KB
#pragma unroll
    for (int m = 0; m < 8; ++m) red[wave][m][lane] = acc[m];
    __syncthreads();

    // Block's outputs: 8 m x 256 d = 512 float4; 256 threads x 2.
#pragma unroll
    for (int r = 0; r < 2; ++r) {
        const int o  = (int)threadIdx.x + r * 256;  // 0..511
        const int m  = o >> 6;
        const int dp = o & 63;
        float4 v = red[0][m][dp];
#pragma unroll
        for (int w = 1; w < 4; ++w) {
            const float4 u = red[w][m][dp];
            v.x = fmaxf(v.x, u.x);
            v.y = fmaxf(v.y, u.y);
            v.z = fmaxf(v.z, u.z);
            v.w = fmaxf(v.w, u.w);
        }
        // ws layout: [lh][b][m][d]
        ((float4*)(ws + ((size_t)lh * BB * MM * DD) +
                   ((size_t)(b * MM + m0 + m)) * DD + dch * 256))[dp] = v;
    }
}

// Kernel2: out = elementwise max of the 4 lh partials. B*M*D/4 float4.
__global__ __launch_bounds__(256) void mention_max_merge(
    const float* __restrict__ ws, float* __restrict__ out)
{
    const int i = (int)(blockIdx.x * blockDim.x + threadIdx.x);  // float4 idx
    const size_t half = (size_t)BB * MM * DD;
    float4 v = ((const float4*)ws)[i];
#pragma unroll
    for (int p = 1; p < 4; ++p) {
        const float4 u = ((const float4*)(ws + p * half))[i];
        v.x = fmaxf(v.x, u.x);
        v.y = fmaxf(v.y, u.y);
        v.z = fmaxf(v.z, u.z);
        v.w = fmaxf(v.w, u.w);
    }
    ((float4*)out)[i] = v;
}

extern "C" void kernel_launch(void* const* d_in, const int* in_sizes, int n_in,
                              void* d_out, int out_size, void* d_ws, size_t ws_size,
                              hipStream_t stream) {
    const float* h    = (const float*)d_in[0];
    const int*   mask = (const int*)d_in[1];
    float*       out  = (float*)d_out;
    float*       ws   = (float*)d_ws;
    dim3 grid1(DD / 256, (MM / 8) * 4, BB);
    mention_max_part<<<grid1, dim3(256), 0, stream>>>(h, mask, ws);
    const int n4 = BB * MM * DD / 4;       // 98304 float4
    mention_max_merge<<<n4 / 256, dim3(256), 0, stream>>>(ws, out);
}

// Round 6
// 72.244 us; speedup vs baseline: 1.3066x; 1.0010x over previous
//
#include <hip/hip_runtime.h>

#define BB 4
#define MM 128
#define LL 512
#define DD 768
#define NEGF (-1e30f)

struct F3 { float x, y, z; };

// Single kernel, single dispatch, no workspace.
// Grid (4 dch, 16 mch, 4 b) = 256 blocks -> exactly 1 block/CU.
// Block = 512 thr = 8 waves; wave w owns l in [w*64, w*64+64) (full L=512
// covered in-block -> no cross-block merge). Lane holds float3 of d
// (d-chunk 192). One 64-bit ballot per (wave, m). Rows staged in two 32-row
// register banks; bank1 loads issue before bank0 compute (prefetch), mask
// loads issue first so their vmcnt retires first. Inner: add-pair + v_max3
// = 1.5 VALU/elem, exactly reference arithmetic (h + {0,-1e30} then max).
__global__ __launch_bounds__(512, 2) void mention_max_kernel(
    const float* __restrict__ h, const int* __restrict__ mask,
    float* __restrict__ out)
{
    const int lane = threadIdx.x & 63;
    const int wave = threadIdx.x >> 6;   // 0..7
    const int dch  = blockIdx.x;         // 0..3
    const int mch  = blockIdx.y;         // 0..15
    const int b    = blockIdx.z;         // 0..3

    const int d0 = dch * 192 + lane * 3;
    const int m0 = mch * 8;
    const int l0 = wave * 64;

    // 1) mask loads first (oldest vmcnt slots -> ballots don't wait on h).
    const int* mp = mask + ((size_t)(b * MM + m0)) * LL + l0 + lane;
    int mv[8];
#pragma unroll
    for (int m = 0; m < 8; ++m) mv[m] = mp[m * LL];

    // 2) stage-0 h loads (rows l0..l0+31).
    const F3* hp = (const F3*)(h + ((size_t)(b * LL + l0)) * DD + d0);
    F3 r0[32];
#pragma unroll
    for (int i = 0; i < 32; ++i) r0[i] = hp[(size_t)i * (DD / 3)];

    // 3) ballots (waits only on mask loads).
    unsigned lobits[8], hibits[8];
#pragma unroll
    for (int m = 0; m < 8; ++m) {
        unsigned long long bl = __ballot(mv[m] != 0);
        lobits[m] = (unsigned)bl;
        hibits[m] = (unsigned)(bl >> 32);
    }

    // 4) stage-1 h loads in flight while stage-0 computes.
    F3 r1[32];
#pragma unroll
    for (int i = 0; i < 32; ++i) r1[i] = hp[(size_t)(i + 32) * (DD / 3)];

    F3 acc[8];
#pragma unroll
    for (int m = 0; m < 8; ++m) { acc[m].x = NEGF; acc[m].y = NEGF; acc[m].z = NEGF; }

    // 5) compute stage 0 (bits 0..31) across all m, then stage 1.
#pragma unroll
    for (int m = 0; m < 8; ++m) {
        const unsigned w32 = lobits[m];
        F3 a = acc[m];
#pragma unroll
        for (int i = 0; i < 32; i += 2) {
            const float ad0 = ((w32 >> i) & 1u) ? 0.0f : NEGF;
            const float ad1 = ((w32 >> (i + 1)) & 1u) ? 0.0f : NEGF;
            a.x = fmaxf(fmaxf(r0[i].x + ad0, r0[i + 1].x + ad1), a.x);
            a.y = fmaxf(fmaxf(r0[i].y + ad0, r0[i + 1].y + ad1), a.y);
            a.z = fmaxf(fmaxf(r0[i].z + ad0, r0[i + 1].z + ad1), a.z);
        }
        acc[m] = a;
    }
#pragma unroll
    for (int m = 0; m < 8; ++m) {
        const unsigned w32 = hibits[m];
        F3 a = acc[m];
#pragma unroll
        for (int i = 0; i < 32; i += 2) {
            const float ad0 = ((w32 >> i) & 1u) ? 0.0f : NEGF;
            const float ad1 = ((w32 >> (i + 1)) & 1u) ? 0.0f : NEGF;
            a.x = fmaxf(fmaxf(r1[i].x + ad0, r1[i + 1].x + ad1), a.x);
            a.y = fmaxf(fmaxf(r1[i].y + ad0, r1[i + 1].y + ad1), a.y);
            a.z = fmaxf(fmaxf(r1[i].z + ad0, r1[i + 1].z + ad1), a.z);
        }
        acc[m] = a;
    }

    // 6) 8-wave tree reduce, component-split (conflict-free, 48 KB).
    __shared__ float red[8][8][3][64];
#pragma unroll
    for (int m = 0; m < 8; ++m) {
        red[wave][m][0][lane] = acc[m].x;
        red[wave][m][1][lane] = acc[m].y;
        red[wave][m][2][lane] = acc[m].z;
    }
    __syncthreads();

    // 512 threads -> 8 m x 64 lanes, one float3 output each.
    {
        const int m  = (int)(threadIdx.x >> 6);
        const int ln = (int)(threadIdx.x & 63);
        float vx = red[0][m][0][ln];
        float vy = red[0][m][1][ln];
        float vz = red[0][m][2][ln];
#pragma unroll
        for (int w = 1; w < 8; ++w) {
            vx = fmaxf(vx, red[w][m][0][ln]);
            vy = fmaxf(vy, red[w][m][1][ln]);
            vz = fmaxf(vz, red[w][m][2][ln]);
        }
        float* op = out + ((size_t)(b * MM + m0 + m)) * DD + dch * 192 + ln * 3;
        op[0] = vx;
        op[1] = vy;
        op[2] = vz;
    }
}

extern "C" void kernel_launch(void* const* d_in, const int* in_sizes, int n_in,
                              void* d_out, int out_size, void* d_ws, size_t ws_size,
                              hipStream_t stream) {
    const float* h    = (const float*)d_in[0];
    const int*   mask = (const int*)d_in[1];
    float*       out  = (float*)d_out;
    dim3 grid(DD / 192, MM / 8, BB);
    mention_max_kernel<<<grid, dim3(512), 0, stream>>>(h, mask, out);
}